// Round 4
// baseline (270.106 us; speedup 1.0000x reference)
//
#include <hip/hip_runtime.h>
#include <hip/hip_fp16.h>

// ResidualDenoiser: 4 chained GEMMs + BN/ReLU + ragged segment softmax.
// Activations live in one persistent fp16 buffer H[8192][3328] laid out
// [A3 | A2 | A1 | A0=x] so each layer's concatenated input is H + colOff.
//   layer0: in H+3072 (K= 256) -> out cols 2048:3072
//   layer1: in H+2048 (K=1280) -> out cols 1024:2048
//   layer2: in H+1024 (K=2304) -> out cols    0:1024
//   layer3: in H+0    (K=3328) -> splitK=4 atomicAdd fp32 into out (bias
//           pre-applied by prep), then separate segment-softmax dispatch.
// LESSONS:
//  R4-R6: in-kernel cross-block sync costs 300-450 us — keep dispatches.
//  R7 (FAILED): launch_bounds(512,2) -> 128-reg cap -> spill.
//  R8/R9 (NEUTRAL, 43-45us/layer2): barrier topology (4-barrier phased vs
//    1-barrier skewed vs 2-barrier syncthreads) does NOT move perf. Math:
//    per CU-K-tile, 8x(64x64)-wave geometry needs 1536cy LDS-read +375cy
//    LDS-write vs 1318cy MFMA; observed 2886cy = fully serialized, and
//    even perfect overlap is LDS-bound. Geometry, not schedule.
//  R10 (this round): 4 waves of 128x64 per block (256 thr). LDS reads
//    ~ (1/Mw+1/Nw): 25% less -> 1129cy < MFMA 1318cy: MFMA-critical at
//    last. 1 wave/SIMD but 512-reg budget -> acc[8][4] (128 AGPR) + 24
//    live frags, full-iteration compiler scheduling window, single
//    barrier per K-tile, 3 LDS buffers, counted vmcnt(12).
// Buffer rotation safety (3 buffers, prefetch distance 2, 1 barrier/iter):
//  staging at iter t targets buf (t+2)%3 == buf (t-1)%3, whose readers
//  finished before barrier B(t-1); staging issues after B(t-1). vmcnt(12)
//  at iter t end leaves only tile t+2's 12 loads outstanding -> tile t+1
//  landed; B(t) publishes it CU-wide before iter t+1 reads it.

#define LDH 3328
#define NROWS 8192

typedef _Float16 f16x8 __attribute__((ext_vector_type(8)));
typedef _Float16 f16x4 __attribute__((ext_vector_type(4)));
typedef float f32x4 __attribute__((ext_vector_type(4)));

__constant__ int c_bnd[11] = {0, 2, 5, 10, 18, 31, 52, 86, 141, 230, 256};

// async global->LDS, 16B per lane; LDS dest is wave-uniform base + lane*16.
__device__ __forceinline__ void async_cp16(const _Float16* g, _Float16* l) {
  __builtin_amdgcn_global_load_lds(
      (__attribute__((address_space(1))) void*)g,
      (__attribute__((address_space(3))) void*)l, 16, 0, 0);
}

__device__ __forceinline__ _Float16 f2h(float f) { return (_Float16)f; }

// ---------------------------------------------------------------------------
// prep: weights fp32->fp16 (contiguous), x staged into H, out = bias.
// One float4-group per thread.
__global__ void prep_kernel(const float* __restrict__ s0,
                            const float* __restrict__ s1,
                            const float* __restrict__ s2,
                            const float* __restrict__ s3,
                            const float* __restrict__ x,
                            const float* __restrict__ b3,
                            _Float16* __restrict__ d0,
                            _Float16* __restrict__ d1,
                            _Float16* __restrict__ d2,
                            _Float16* __restrict__ d3,
                            _Float16* __restrict__ H, float* __restrict__ out,
                            int n0, int n1, int n2, int n3, int n4, int n5) {
  int i = blockIdx.x * blockDim.x + threadIdx.x;
  if (i >= n5) return;
  if (i >= n4) {  // out[8192][256] = broadcast bias b3
    const int j = i - n4;
    const int c = (j & 63) * 4;
    *(float4*)&out[(size_t)j * 4] = *(const float4*)&b3[c];
    return;
  }
  if (i >= n3) {  // x[8192,256] -> H[:, 3072:3328]
    const int j = i - n3;
    const int row = j >> 6;
    const int c = (j & 63) * 4;
    const float4 v = *(const float4*)&x[(size_t)j * 4];
    f16x4 h = {f2h(v.x), f2h(v.y), f2h(v.z), f2h(v.w)};
    *(f16x4*)&H[(size_t)row * LDH + 3072 + c] = h;
    return;
  }
  const float* s;
  _Float16* d;
  if (i < n0) {
    s = s0; d = d0;
  } else if (i < n1) {
    s = s1 - (size_t)n0 * 4; d = d1 - (size_t)n0 * 4;
  } else if (i < n2) {
    s = s2 - (size_t)n1 * 4; d = d2 - (size_t)n1 * 4;
  } else {
    s = s3 - (size_t)n2 * 4; d = d3 - (size_t)n2 * 4;
  }
  const float4 v = *(const float4*)&s[(size_t)i * 4];
  f16x4 h = {f2h(v.x), f2h(v.y), f2h(v.z), f2h(v.w)};
  *(f16x4*)&d[(size_t)i * 4] = h;
}

// ---------------------------------------------------------------------------
// Shared 4-wave 256x128 K-loop (BK=64, 3 LDS buffers, counted vmcnt).
// Wave tile 128x64 (2M x 2N wave grid). LDS per buffer: A[256][64] then
// B[128][64], f16. Row = 8 chunks of 16B; chunk c of row r at slot c^(r&7)
// (XOR swizzle on the GLOBAL source address; LDS dest stays linear).

#define BUFSZ 24576  /* f16 elems per buffer: 256*64 + 128*64 */
#define ABOFF 16384  /* B tile offset inside buffer */

// stage one 32-row group (256 threads = 1 instr covers 32 rows x 8 chunks).
#define STA(Ab, q, k0)                                                       \
  async_cp16(A + (size_t)(row0 + (q) * 32 + srow) * LDH + (k0) + sgc,        \
             (Ab) + ((q) * 32 + wave * 8) * 64)
#define STB(Bb, h, k0)                                                       \
  async_cp16(W + (size_t)(col0 + (h) * 32 + srow) * K + (k0) + sgc,          \
             (Bb) + ((h) * 32 + wave * 8) * 64)

// Load 12 fragments (8 A + 4 B) for 32-wide k-slice KQ.
#define LOADK(AV, BV, KQ)                                                     \
  {                                                                           \
    _Pragma("unroll") for (int t = 0; t < 8; ++t) {                           \
      const int ra = wr * 128 + t * 16 + fr;                                  \
      AV[t] =                                                                 \
          *(const f16x8*)&Ac[ra * 64 + (((q2 + 4 * (KQ)) ^ (ra & 7)) * 8)];   \
    }                                                                         \
    _Pragma("unroll") for (int t = 0; t < 4; ++t) {                           \
      const int rb = wc * 64 + t * 16 + fr;                                   \
      BV[t] =                                                                 \
          *(const f16x8*)&Bc[rb * 64 + (((q2 + 4 * (KQ)) ^ (rb & 7)) * 8)];   \
    }                                                                         \
  }

#define MF(a, b, c) __builtin_amdgcn_mfma_f32_16x16x32_f16(a, b, c, 0, 0, 0)

#define MFMAK(AV, BV)                                                         \
  _Pragma("unroll") for (int tm = 0; tm < 8; ++tm)                            \
      _Pragma("unroll") for (int tn = 0; tn < 4; ++tn) acc[tm][tn] =          \
          MF(AV[tm], BV[tn], acc[tm][tn]);

// One K-tile iteration, ONE barrier. Interior scheduling left to the
// compiler (plain LDS loads -> fine-grained lgkmcnt interleave with MFMA).
#define GITER1(STG, VM, k0n)                                                  \
  {                                                                           \
    _Float16* Ac = lds_ + cur * BUFSZ;                                        \
    _Float16* Bc = Ac + ABOFF;                                                \
    _Float16* An = lds_ + nxt * BUFSZ;                                        \
    _Float16* Bn = An + ABOFF;                                                \
    f16x8 av0[8], bv0[4], av1[8], bv1[4];                                     \
    if (STG) { STA(An, 0, k0n); STA(An, 1, k0n); STA(An, 2, k0n);             \
               STA(An, 3, k0n); }                                             \
    LOADK(av0, bv0, 0);                                                       \
    if (STG) { STA(An, 4, k0n); STA(An, 5, k0n); STA(An, 6, k0n);             \
               STA(An, 7, k0n); }                                             \
    LOADK(av1, bv1, 1);                                                       \
    if (STG) { STB(Bn, 0, k0n); STB(Bn, 1, k0n); STB(Bn, 2, k0n);             \
               STB(Bn, 3, k0n); }                                             \
    __builtin_amdgcn_s_setprio(1);                                            \
    MFMAK(av0, bv0);                                                          \
    MFMAK(av1, bv1);                                                          \
    __builtin_amdgcn_s_setprio(0);                                            \
    asm volatile("s_waitcnt " VM ::: "memory");                               \
    __builtin_amdgcn_s_barrier();                                             \
  }

__device__ __forceinline__ void gemm_loop(const _Float16* __restrict__ A,
                                          const _Float16* __restrict__ W,
                                          int K, int kbase, int nt, int row0,
                                          int col0, int tid, _Float16* lds_,
                                          f32x4 (&acc)[8][4]) {
  const int lane = tid & 63;
  const int wave = tid >> 6;   // 0..3
  const int wr = wave >> 1;    // 0..1 : 128-row slice
  const int wc = wave & 1;     // 0..1 : 64-col slice
  const int fr = lane & 15;
  const int q2 = lane >> 4;
  const int srow = tid >> 3;                       // staging row 0..31
  const int sgc = ((tid & 7) ^ (srow & 7)) * 8;    // pre-swizzled chunk

  // prologue: stage tiles 0 and 1 (24 instrs), validate tile 0.
  {
    _Float16* A0 = lds_;
    _Float16* B0 = lds_ + ABOFF;
#pragma unroll
    for (int q = 0; q < 8; ++q) STA(A0, q, kbase);
#pragma unroll
    for (int h = 0; h < 4; ++h) STB(B0, h, kbase);
    _Float16* A1 = lds_ + BUFSZ;
    _Float16* B1 = A1 + ABOFF;
#pragma unroll
    for (int q = 0; q < 8; ++q) STA(A1, q, kbase + 64);
#pragma unroll
    for (int h = 0; h < 4; ++h) STB(B1, h, kbase + 64);
    asm volatile("s_waitcnt vmcnt(12)" ::: "memory");  // tile 0 landed
    __builtin_amdgcn_s_barrier();
  }

  int cur = 0, nxt = 2;
  for (int t = 0; t + 2 < nt; ++t) {
    GITER1(1, "vmcnt(12)", kbase + (t + 2) * 64);
    cur = cur == 2 ? 0 : cur + 1;
    nxt = nxt == 2 ? 0 : nxt + 1;
  }
  GITER1(0, "vmcnt(0)", 0);  // t = nt-2: drain, validates tile nt-1
  cur = cur == 2 ? 0 : cur + 1;
  GITER1(0, "vmcnt(0)", 0);  // t = nt-1: vmcnt(0) is free (0 outstanding)
}

// ---------------------------------------------------------------------------
// Layers 0-2: C = relu(bn(A[256,K] @ W[128,K]^T)) -> fp16 into H.
// Grid dim3(32,8), 256 threads (4 waves), 144 KB dynamic LDS.
__launch_bounds__(256, 1) __global__
void gemm_bn_w4(const _Float16* __restrict__ A, int K,
                const _Float16* __restrict__ W,
                const float* __restrict__ bias,
                const float* __restrict__ g, const float* __restrict__ be,
                const float* __restrict__ rm, const float* __restrict__ rv,
                _Float16* __restrict__ outH, int outOff) {
  extern __shared__ _Float16 lds_[];
  const int tid = threadIdx.x;
  const int lane = tid & 63;
  const int wave = tid >> 6;
  const int wr = wave >> 1;
  const int wc = wave & 1;
  const int fr = lane & 15;
  const int q2 = lane >> 4;
  const int row0 = blockIdx.x * 256;
  const int col0 = blockIdx.y * 128;

  f32x4 acc[8][4] = {};
  gemm_loop(A, W, K, 0, K >> 6, row0, col0, tid, lds_, acc);

  // Epilogue. C/D layout: col = lane&15, row = (lane>>4)*4 + reg.
#pragma unroll
  for (int tn = 0; tn < 4; ++tn) {
    const int n = col0 + wc * 64 + tn * 16 + fr;
    const float alpha = g[n] * rsqrtf(rv[n] + 1e-5f);
    const float beta = (bias[n] - rm[n]) * alpha + be[n];
#pragma unroll
    for (int tm = 0; tm < 8; ++tm) {
      const int rbase = row0 + wr * 128 + tm * 16 + q2 * 4;
#pragma unroll
      for (int r = 0; r < 4; ++r) {
        float v = acc[tm][tn][r] * alpha + beta;
        v = fmaxf(v, 0.0f);
        outH[(size_t)(rbase + r) * LDH + outOff + n] = f2h(v);
      }
    }
  }
}

// ---------------------------------------------------------------------------
// Layer 3: same loop, splitK=4 (832 = 13*64 per slice). Grid dim3(32,8):
// cb=by&1 (col tile), ks=by>>1. Partials atomicAdd into out (bias
// pre-applied by prep).
__launch_bounds__(256, 1) __global__
void gemm_out_w4(const _Float16* __restrict__ A,
                 const _Float16* __restrict__ W, float* __restrict__ out) {
  extern __shared__ _Float16 lds_[];
  const int tid = threadIdx.x;
  const int lane = tid & 63;
  const int wave = tid >> 6;
  const int wr = wave >> 1;
  const int wc = wave & 1;
  const int fr = lane & 15;
  const int q2 = lane >> 4;
  const int row0 = blockIdx.x * 256;
  const int cb = blockIdx.y & 1;
  const int ks = blockIdx.y >> 1;
  const int col0 = cb * 128;
  const int K = 3328;

  f32x4 acc[8][4] = {};
  gemm_loop(A, W, K, ks * 832, 13, row0, col0, tid, lds_, acc);

#pragma unroll
  for (int tn = 0; tn < 4; ++tn) {
    const int n = col0 + wc * 64 + tn * 16 + fr;
#pragma unroll
    for (int tm = 0; tm < 8; ++tm) {
      const int rbase = row0 + wr * 128 + tm * 16 + q2 * 4;
#pragma unroll
      for (int r = 0; r < 4; ++r)
        atomicAdd(&out[(size_t)(rbase + r) * 256 + n], acc[tm][tn][r]);
    }
  }
}

// ---------------------------------------------------------------------------
// ragged segment softmax, in place on out[8192][256]; 4 rows/block (1/wave).
__global__ void segsoftmax_kernel(float* __restrict__ out,
                                  const int* __restrict__ segids) {
  __shared__ float vals[4][256];
  __shared__ float red[4][10];
  const int w = threadIdx.x >> 6;
  const int l = threadIdx.x & 63;
  const int row = blockIdx.x * 4 + w;
  float4 v = *(float4*)&out[(size_t)row * 256 + l * 4];
  *(float4*)&vals[w][l * 4] = v;
  __syncthreads();
  if (l < 10) {
    float m = -1e30f;
    for (int j = c_bnd[l]; j < c_bnd[l + 1]; ++j) m = fmaxf(m, vals[w][j]);
    red[w][l] = m;
  }
  __syncthreads();
  const int4 s4 = *(const int4*)&segids[l * 4];
  float4 e;
  e.x = expf(v.x - red[w][s4.x]);
  e.y = expf(v.y - red[w][s4.y]);
  e.z = expf(v.z - red[w][s4.z]);
  e.w = expf(v.w - red[w][s4.w]);
  *(float4*)&vals[w][l * 4] = e;
  __syncthreads();
  if (l < 10) {
    float s = 0.0f;
    for (int j = c_bnd[l]; j < c_bnd[l + 1]; ++j) s += vals[w][j];
    red[w][l] = s;
  }
  __syncthreads();
  float4 o;
  o.x = e.x / red[w][s4.x];
  o.y = e.y / red[w][s4.y];
  o.z = e.z / red[w][s4.z];
  o.w = e.w / red[w][s4.w];
  *(float4*)&out[(size_t)row * 256 + l * 4] = o;
}

// ---------------------------------------------------------------------------
extern "C" void kernel_launch(void* const* d_in, const int* in_sizes, int n_in,
                              void* d_out, int out_size, void* d_ws,
                              size_t ws_size, hipStream_t stream) {
  const float* x = (const float*)d_in[0];
  const float* W0 = (const float*)d_in[1];
  const float* b0 = (const float*)d_in[2];
  const float* g0 = (const float*)d_in[3];
  const float* be0 = (const float*)d_in[4];
  const float* rm0 = (const float*)d_in[5];
  const float* rv0 = (const float*)d_in[6];
  const float* W1 = (const float*)d_in[7];
  const float* b1 = (const float*)d_in[8];
  const float* g1 = (const float*)d_in[9];
  const float* be1 = (const float*)d_in[10];
  const float* rm1 = (const float*)d_in[11];
  const float* rv1 = (const float*)d_in[12];
  const float* W2 = (const float*)d_in[13];
  const float* b2 = (const float*)d_in[14];
  const float* g2 = (const float*)d_in[15];
  const float* be2 = (const float*)d_in[16];
  const float* rm2 = (const float*)d_in[17];
  const float* rv2 = (const float*)d_in[18];
  const float* W3 = (const float*)d_in[19];
  const float* b3 = (const float*)d_in[20];
  const int* seg = (const int*)d_in[21];
  float* out = (float*)d_out;

  // ws (fp16): H[8192*3328] | Wh0 | Wh1 | Wh2 | Wh3  (~64.1 MB)
  _Float16* H = (_Float16*)d_ws;
  size_t off = (size_t)NROWS * LDH;
  _Float16* Wh0 = H + off; off += 1024 * 256;
  _Float16* Wh1 = H + off; off += 1024 * 1280;
  _Float16* Wh2 = H + off; off += 1024 * 2304;
  _Float16* Wh3 = H + off;

  static bool attr_done = false;
  if (!attr_done) {
    hipFuncSetAttribute(reinterpret_cast<const void*>(gemm_bn_w4),
                        hipFuncAttributeMaxDynamicSharedMemorySize, 147456);
    hipFuncSetAttribute(reinterpret_cast<const void*>(gemm_out_w4),
                        hipFuncAttributeMaxDynamicSharedMemorySize, 147456);
    attr_done = true;
  }

  // cumulative float4 counts: W0, W1, W2, W3, x, out-init
  const int n0 = 65536, n1 = n0 + 327680, n2 = n1 + 589824, n3 = n2 + 212992;
  const int n4 = n3 + 524288, n5 = n4 + 524288;
  prep_kernel<<<(n5 + 255) / 256, 256, 0, stream>>>(
      W0, W1, W2, W3, x, b3, Wh0, Wh1, Wh2, Wh3, H, out, n0, n1, n2, n3, n4,
      n5);

  gemm_bn_w4<<<dim3(32, 8), 256, 147456, stream>>>(
      H + 3072, 256, Wh0, b0, g0, be0, rm0, rv0, H, 2048);
  gemm_bn_w4<<<dim3(32, 8), 256, 147456, stream>>>(
      H + 2048, 1280, Wh1, b1, g1, be1, rm1, rv1, H, 1024);
  gemm_bn_w4<<<dim3(32, 8), 256, 147456, stream>>>(
      H + 1024, 2304, Wh2, b2, g2, be2, rm2, rv2, H, 0);
  gemm_out_w4<<<dim3(32, 8), 256, 147456, stream>>>(H, Wh3, out);
  segsoftmax_kernel<<<2048, 256, 0, stream>>>(out, seg);
}

// Round 5
// 248.020 us; speedup vs baseline: 1.0891x; 1.0891x over previous
//
#include <hip/hip_runtime.h>
#include <hip/hip_fp16.h>

// ResidualDenoiser: 4 chained GEMMs + BN/ReLU + ragged segment softmax.
// Activations live in one persistent fp16 buffer H[8192][3328] laid out
// [A3 | A2 | A1 | A0=x] so each layer's concatenated input is H + colOff.
//   layer0: in H+3072 (K= 256) -> out cols 2048:3072
//   layer1: in H+2048 (K=1280) -> out cols 1024:2048
//   layer2: in H+1024 (K=2304) -> out cols    0:1024
//   layer3: in H+0    (K=3328) -> splitK=4 atomicAdd fp32 into out (bias
//           pre-applied by prep), then separate segment-softmax dispatch.
// LESSONS:
//  R4-R6: in-kernel cross-block sync costs 300-450 us — keep dispatches.
//  R7 (FAILED): launch_bounds(512,2) -> 128-reg cap -> spill.
//  R8/R9 (NEUTRAL 43-45us L2): barrier topology doesn't matter; at 64x64
//    wave tiles the loop is LDS-read-bound (128KB/CU-Ktile = 1506cy > MFMA
//    1318cy; R8 measured 2886cy/tile = serial sum).
//  R10 (FAILED 57us): 4 waves/block = 1 wave/SIMD -> no latency hiding
//    (+ scratch spill, WRITE 27.6MB). Wave-tile growth must keep 2 w/SIMD.
//  R11 (this round): R9's proven 512-thread skeleton (2 w/SIMD, 3-buffer
//    rotation, vmcnt(6), 1 barrier/iter) with waves re-split 4M x 2Khalf:
//    each wave = 64x128 partial tile over 32 of the 64-wide K-tile
//    (acc[4][8] = 128 AGPR). LDS reads/CU-Ktile: 128KB -> 96KB -> loop is
//    MFMA-critical for the first time. kh-pairs reduce via LDS at epilogue.
// Buffer rotation safety: unchanged from R9 (staging at iter t targets
// buf (t+2)%3 whose readers retired before barrier t-1; vmcnt(6) at iter t
// proves tile t+1 landed; barrier publishes).

#define LDH 3328
#define NROWS 8192

typedef _Float16 f16x8 __attribute__((ext_vector_type(8)));
typedef _Float16 f16x4 __attribute__((ext_vector_type(4)));
typedef float f32x4 __attribute__((ext_vector_type(4)));

__constant__ int c_bnd[11] = {0, 2, 5, 10, 18, 31, 52, 86, 141, 230, 256};

// async global->LDS, 16B per lane; LDS dest is wave-uniform base + lane*16.
__device__ __forceinline__ void async_cp16(const _Float16* g, _Float16* l) {
  __builtin_amdgcn_global_load_lds(
      (__attribute__((address_space(1))) void*)g,
      (__attribute__((address_space(3))) void*)l, 16, 0, 0);
}

__device__ __forceinline__ _Float16 f2h(float f) { return (_Float16)f; }

// ---------------------------------------------------------------------------
// prep: weights fp32->fp16 (contiguous), x staged into H, out = bias.
// One float4-group per thread.
__global__ void prep_kernel(const float* __restrict__ s0,
                            const float* __restrict__ s1,
                            const float* __restrict__ s2,
                            const float* __restrict__ s3,
                            const float* __restrict__ x,
                            const float* __restrict__ b3,
                            _Float16* __restrict__ d0,
                            _Float16* __restrict__ d1,
                            _Float16* __restrict__ d2,
                            _Float16* __restrict__ d3,
                            _Float16* __restrict__ H, float* __restrict__ out,
                            int n0, int n1, int n2, int n3, int n4, int n5) {
  int i = blockIdx.x * blockDim.x + threadIdx.x;
  if (i >= n5) return;
  if (i >= n4) {  // out[8192][256] = broadcast bias b3
    const int j = i - n4;
    const int c = (j & 63) * 4;
    *(float4*)&out[(size_t)j * 4] = *(const float4*)&b3[c];
    return;
  }
  if (i >= n3) {  // x[8192,256] -> H[:, 3072:3328]
    const int j = i - n3;
    const int row = j >> 6;
    const int c = (j & 63) * 4;
    const float4 v = *(const float4*)&x[(size_t)j * 4];
    f16x4 h = {f2h(v.x), f2h(v.y), f2h(v.z), f2h(v.w)};
    *(f16x4*)&H[(size_t)row * LDH + 3072 + c] = h;
    return;
  }
  const float* s;
  _Float16* d;
  if (i < n0) {
    s = s0; d = d0;
  } else if (i < n1) {
    s = s1 - (size_t)n0 * 4; d = d1 - (size_t)n0 * 4;
  } else if (i < n2) {
    s = s2 - (size_t)n1 * 4; d = d2 - (size_t)n1 * 4;
  } else {
    s = s3 - (size_t)n2 * 4; d = d3 - (size_t)n2 * 4;
  }
  const float4 v = *(const float4*)&s[(size_t)i * 4];
  f16x4 h = {f2h(v.x), f2h(v.y), f2h(v.z), f2h(v.w)};
  *(f16x4*)&d[(size_t)i * 4] = h;
}

// ---------------------------------------------------------------------------
// Layers 0-2: 8-wave 256x128 block, BK=64, 3 LDS buffers, counted vmcnt.
// Waves: ws=wave>>1 (0..3) = 64-row slice; kh=wave&1 = 32-wide K half.
// Each wave: 64x128 partial tile (acc[4][8]); kh pairs reduced via LDS at
// the epilogue. LDS per buffer: A[256][64] then B[128][64] f16; row = 8
// chunks of 16B, chunk c of row r at slot c^(r&7) (swizzle applied on the
// GLOBAL source address; LDS dest linear).

#define BUFSZ 24576  /* f16 elems per buffer: 256*64 + 128*64 */
#define ABOFF 16384  /* B tile offset inside buffer */

// stage one 64-row group of A (quarter q) / B (half h) of the K-tile at k0.
#define STA(Ab, q, k0)                                                       \
  async_cp16(A + (size_t)(row0 + (q) * 64 + srow) * LDH + (k0) + sgc,        \
             (Ab) + ((q) * 64 + wave * 8) * 64)
#define STB(Bb, h, k0)                                                       \
  async_cp16(W + (size_t)(col0 + (h) * 64 + srow) * K + (k0) + sgc,          \
             (Bb) + ((h) * 64 + wave * 8) * 64)

// Load this wave's 12 fragments (4 A rows-slice + 8 B full-width) for its
// 32-wide k-half (chunk c = q2 + 4*kh).
#define LOADK(AV, BV)                                                         \
  {                                                                           \
    _Pragma("unroll") for (int t = 0; t < 4; ++t) {                           \
      const int ra = ws * 64 + t * 16 + fr;                                   \
      AV[t] = *(const f16x8*)&Ac[ra * 64 + ((ckh ^ (ra & 7)) * 8)];           \
    }                                                                         \
    _Pragma("unroll") for (int u = 0; u < 8; ++u) {                           \
      const int rb = u * 16 + fr;                                             \
      BV[u] = *(const f16x8*)&Bc[rb * 64 + ((ckh ^ (rb & 7)) * 8)];           \
    }                                                                         \
  }

#define MF(a, b, c) __builtin_amdgcn_mfma_f32_16x16x32_f16(a, b, c, 0, 0, 0)

#define MFMAK(AV, BV)                                                         \
  _Pragma("unroll") for (int t = 0; t < 4; ++t)                               \
      _Pragma("unroll") for (int u = 0; u < 8; ++u) acc[t][u] =               \
          MF(AV[t], BV[u], acc[t][u]);

// One K-tile iteration, ONE barrier (R9 skeleton, proven race-free).
#define GITER1(STG, VM, k0n)                                                  \
  {                                                                           \
    _Float16* Ac = lds_ + cur * BUFSZ;                                        \
    _Float16* Bc = Ac + ABOFF;                                                \
    _Float16* An = lds_ + nxt * BUFSZ;                                        \
    _Float16* Bn = An + ABOFF;                                                \
    f16x8 av[4], bv[8];                                                       \
    if (STG) { STA(An, 0, k0n); STA(An, 1, k0n); STB(Bn, 0, k0n); }           \
    if (STG) { STA(An, 2, k0n); STA(An, 3, k0n); STB(Bn, 1, k0n); }           \
    LOADK(av, bv);                                                            \
    __builtin_amdgcn_s_setprio(1);                                            \
    MFMAK(av, bv);                                                            \
    __builtin_amdgcn_s_setprio(0);                                            \
    asm volatile("s_waitcnt " VM ::: "memory");                               \
    __builtin_amdgcn_s_barrier();                                             \
  }

__device__ __forceinline__ void gemm_loop(const _Float16* __restrict__ A,
                                          const _Float16* __restrict__ W,
                                          int K, int kbase, int nt, int row0,
                                          int col0, int tid, _Float16* lds_,
                                          f32x4 (&acc)[4][8]) {
  const int lane = tid & 63;
  const int wave = tid >> 6;   // 0..7
  const int ws = wave >> 1;    // 0..3 : 64-row slice
  const int kh = wave & 1;     // 0..1 : 32-wide k half
  const int fr = lane & 15;
  const int q2 = lane >> 4;
  const int ckh = q2 + 4 * kh;                     // this wave's k chunk
  const int srow = tid >> 3;                       // staging row 0..63
  const int sgc = ((tid & 7) ^ (srow & 7)) * 8;    // pre-swizzled chunk

  // prologue: stage tiles 0 and 1 (12 loads), validate tile 0.
  {
    _Float16* A0 = lds_;
    _Float16* B0 = lds_ + ABOFF;
    STA(A0, 0, kbase); STA(A0, 1, kbase); STA(A0, 2, kbase); STA(A0, 3, kbase);
    STB(B0, 0, kbase); STB(B0, 1, kbase);
    _Float16* A1 = lds_ + BUFSZ;
    _Float16* B1 = A1 + ABOFF;
    STA(A1, 0, kbase + 64); STA(A1, 1, kbase + 64);
    STA(A1, 2, kbase + 64); STA(A1, 3, kbase + 64);
    STB(B1, 0, kbase + 64); STB(B1, 1, kbase + 64);
    asm volatile("s_waitcnt vmcnt(6)" ::: "memory");  // tile 0 landed
    __builtin_amdgcn_s_barrier();
  }

  int cur = 0, nxt = 2;
  for (int t = 0; t + 2 < nt; ++t) {
    GITER1(1, "vmcnt(6)", kbase + (t + 2) * 64);
    cur = cur == 2 ? 0 : cur + 1;
    nxt = nxt == 2 ? 0 : nxt + 1;
  }
  GITER1(0, "vmcnt(0)", 0);  // t = nt-2: drain, validates tile nt-1
  cur = cur == 2 ? 0 : cur + 1;
  GITER1(0, "vmcnt(0)", 0);  // t = nt-1: vmcnt(0) is free (0 outstanding)
}

// ---------------------------------------------------------------------------
// Layers 0-2: C = relu(bn(A[256,K] @ W[128,K]^T)) -> fp16 into H.
// Grid dim3(32,8), 512 threads, 144 KB dynamic LDS (8 waves, 2/SIMD).
__launch_bounds__(512, 1) __global__
void gemm_bn_ks(const _Float16* __restrict__ A, int K,
                const _Float16* __restrict__ W,
                const float* __restrict__ bias,
                const float* __restrict__ g, const float* __restrict__ be,
                const float* __restrict__ rm, const float* __restrict__ rv,
                _Float16* __restrict__ outH, int outOff) {
  extern __shared__ _Float16 lds_[];
  const int tid = threadIdx.x;
  const int lane = tid & 63;
  const int wave = tid >> 6;
  const int ws = wave >> 1;
  const int kh = wave & 1;
  const int fr = lane & 15;
  const int q2 = lane >> 4;
  const int row0 = blockIdx.x * 256;
  const int col0 = blockIdx.y * 128;

  f32x4 acc[4][8] = {};
  gemm_loop(A, W, K, 0, K >> 6, row0, col0, tid, lds_, acc);

  // Epilogue: kh=1 dumps partials to LDS; kh=0 adds, applies BN, stores.
  // Exchange region ws: 64x128 f32 = 32KB (4 regions = 128KB <= 144KB).
  float* xch = (float*)lds_;
  if (kh) {
#pragma unroll
    for (int t = 0; t < 4; ++t)
#pragma unroll
      for (int u = 0; u < 8; ++u)
        *(f32x4*)&xch[ws * 8192 + (t * 8 + u) * 256 + lane * 4] = acc[t][u];
  }
  __syncthreads();
  if (!kh) {
#pragma unroll
    for (int u = 0; u < 8; ++u) {
      const int n = col0 + u * 16 + fr;
      const float alpha = g[n] * rsqrtf(rv[n] + 1e-5f);
      const float beta = (bias[n] - rm[n]) * alpha + be[n];
#pragma unroll
      for (int t = 0; t < 4; ++t) {
        const f32x4 p = *(const f32x4*)&xch[ws * 8192 + (t * 8 + u) * 256 +
                                            lane * 4];
        const int rbase = row0 + ws * 64 + t * 16 + q2 * 4;
#pragma unroll
        for (int r = 0; r < 4; ++r) {
          float v = (acc[t][u][r] + p[r]) * alpha + beta;
          v = fmaxf(v, 0.0f);
          outH[(size_t)(rbase + r) * LDH + outOff + n] = f2h(v);
        }
      }
    }
  }
}

// ---------------------------------------------------------------------------
// Layer 3 (R0-proven body): splitK=4, BK=64. Grid dim3(64,8): cb=by&1,
// ks=by>>1. Partials atomicAdd into out (bias pre-applied by prep).
__launch_bounds__(256, 4) __global__
void gemm_out_kernel(const _Float16* __restrict__ A,
                     const _Float16* __restrict__ W,
                     float* __restrict__ out) {
  __shared__ _Float16 Alds[128 * 64];
  __shared__ _Float16 Blds[128 * 64];

  const int tid = threadIdx.x;
  const int lane = tid & 63;
  const int wave = tid >> 6;
  const int wr = wave >> 1;
  const int wc = wave & 1;
  const int row0 = blockIdx.x * 128;
  const int cb = blockIdx.y & 1;
  const int ks = blockIdx.y >> 1;
  const int col0 = cb * 128;
  const int k0b = ks * 832;
  const int k0e = k0b + 832;
  const int lr = lane >> 3;  // staging: 8 rows x 8 16B-chunks
  const int ls = lane & 7;
  const int lc = ls ^ lr;
  const int fr = lane & 15;
  const int q = lane >> 4;
  const int K = 3328;

  f32x4 acc[4][4] = {};

  for (int k0 = k0b; k0 < k0e; k0 += 64) {
    __syncthreads();
#pragma unroll
    for (int it = 0; it < 4; ++it) {
      const int rl = it * 32 + wave * 8;
      async_cp16(A + (size_t)(row0 + rl + lr) * LDH + k0 + lc * 8,
                 &Alds[rl * 64]);
      async_cp16(W + (size_t)(col0 + rl + lr) * K + k0 + lc * 8,
                 &Blds[rl * 64]);
    }
    __syncthreads();

#pragma unroll
    for (int kq = 0; kq < 2; ++kq) {
      f16x8 av[4], bv[4];
#pragma unroll
      for (int t = 0; t < 4; ++t) {
        const int ra = wr * 64 + t * 16 + fr;
        av[t] = *(const f16x8*)&Alds[ra * 64 + (((q + 4 * kq) ^ (ra & 7)) * 8)];
        const int rb = wc * 64 + t * 16 + fr;
        bv[t] = *(const f16x8*)&Blds[rb * 64 + (((q + 4 * kq) ^ (rb & 7)) * 8)];
      }
#pragma unroll
      for (int tm = 0; tm < 4; ++tm)
#pragma unroll
        for (int tn = 0; tn < 4; ++tn)
          acc[tm][tn] = __builtin_amdgcn_mfma_f32_16x16x32_f16(
              av[tm], bv[tn], acc[tm][tn], 0, 0, 0);
    }
  }

#pragma unroll
  for (int tn = 0; tn < 4; ++tn) {
    const int n = col0 + wc * 64 + tn * 16 + fr;
#pragma unroll
    for (int tm = 0; tm < 4; ++tm) {
      const int rbase = row0 + wr * 64 + tm * 16 + q * 4;
#pragma unroll
      for (int r = 0; r < 4; ++r)
        atomicAdd(&out[(size_t)(rbase + r) * 256 + n], acc[tm][tn][r]);
    }
  }
}

// ---------------------------------------------------------------------------
// ragged segment softmax, in place on out[8192][256]; 4 rows/block (1/wave).
__global__ void segsoftmax_kernel(float* __restrict__ out,
                                  const int* __restrict__ segids) {
  __shared__ float vals[4][256];
  __shared__ float red[4][10];
  const int w = threadIdx.x >> 6;
  const int l = threadIdx.x & 63;
  const int row = blockIdx.x * 4 + w;
  float4 v = *(float4*)&out[(size_t)row * 256 + l * 4];
  *(float4*)&vals[w][l * 4] = v;
  __syncthreads();
  if (l < 10) {
    float m = -1e30f;
    for (int j = c_bnd[l]; j < c_bnd[l + 1]; ++j) m = fmaxf(m, vals[w][j]);
    red[w][l] = m;
  }
  __syncthreads();
  const int4 s4 = *(const int4*)&segids[l * 4];
  float4 e;
  e.x = expf(v.x - red[w][s4.x]);
  e.y = expf(v.y - red[w][s4.y]);
  e.z = expf(v.z - red[w][s4.z]);
  e.w = expf(v.w - red[w][s4.w]);
  *(float4*)&vals[w][l * 4] = e;
  __syncthreads();
  if (l < 10) {
    float s = 0.0f;
    for (int j = c_bnd[l]; j < c_bnd[l + 1]; ++j) s += vals[w][j];
    red[w][l] = s;
  }
  __syncthreads();
  float4 o;
  o.x = e.x / red[w][s4.x];
  o.y = e.y / red[w][s4.y];
  o.z = e.z / red[w][s4.z];
  o.w = e.w / red[w][s4.w];
  *(float4*)&out[(size_t)row * 256 + l * 4] = o;
}

// ---------------------------------------------------------------------------
extern "C" void kernel_launch(void* const* d_in, const int* in_sizes, int n_in,
                              void* d_out, int out_size, void* d_ws,
                              size_t ws_size, hipStream_t stream) {
  const float* x = (const float*)d_in[0];
  const float* W0 = (const float*)d_in[1];
  const float* b0 = (const float*)d_in[2];
  const float* g0 = (const float*)d_in[3];
  const float* be0 = (const float*)d_in[4];
  const float* rm0 = (const float*)d_in[5];
  const float* rv0 = (const float*)d_in[6];
  const float* W1 = (const float*)d_in[7];
  const float* b1 = (const float*)d_in[8];
  const float* g1 = (const float*)d_in[9];
  const float* be1 = (const float*)d_in[10];
  const float* rm1 = (const float*)d_in[11];
  const float* rv1 = (const float*)d_in[12];
  const float* W2 = (const float*)d_in[13];
  const float* b2 = (const float*)d_in[14];
  const float* g2 = (const float*)d_in[15];
  const float* be2 = (const float*)d_in[16];
  const float* rm2 = (const float*)d_in[17];
  const float* rv2 = (const float*)d_in[18];
  const float* W3 = (const float*)d_in[19];
  const float* b3 = (const float*)d_in[20];
  const int* seg = (const int*)d_in[21];
  float* out = (float*)d_out;

  // ws (fp16): H[8192*3328] | Wh0 | Wh1 | Wh2 | Wh3  (~64.1 MB)
  _Float16* H = (_Float16*)d_ws;
  size_t off = (size_t)NROWS * LDH;
  _Float16* Wh0 = H + off; off += 1024 * 256;
  _Float16* Wh1 = H + off; off += 1024 * 1280;
  _Float16* Wh2 = H + off; off += 1024 * 2304;
  _Float16* Wh3 = H + off;

  static bool attr_done = false;
  if (!attr_done) {
    hipFuncSetAttribute(reinterpret_cast<const void*>(gemm_bn_ks),
                        hipFuncAttributeMaxDynamicSharedMemorySize, 147456);
    attr_done = true;
  }

  // cumulative float4 counts: W0, W1, W2, W3, x, out-init
  const int n0 = 65536, n1 = n0 + 327680, n2 = n1 + 589824, n3 = n2 + 212992;
  const int n4 = n3 + 524288, n5 = n4 + 524288;
  prep_kernel<<<(n5 + 255) / 256, 256, 0, stream>>>(
      W0, W1, W2, W3, x, b3, Wh0, Wh1, Wh2, Wh3, H, out, n0, n1, n2, n3, n4,
      n5);

  gemm_bn_ks<<<dim3(32, 8), 512, 147456, stream>>>(
      H + 3072, 256, Wh0, b0, g0, be0, rm0, rv0, H, 2048);
  gemm_bn_ks<<<dim3(32, 8), 512, 147456, stream>>>(
      H + 2048, 1280, Wh1, b1, g1, be1, rm1, rv1, H, 1024);
  gemm_bn_ks<<<dim3(32, 8), 512, 147456, stream>>>(
      H + 1024, 2304, Wh2, b2, g2, be2, rm2, rv2, H, 0);
  gemm_out_kernel<<<dim3(64, 8), 256, 0, stream>>>(H, Wh3, out);
  segsoftmax_kernel<<<2048, 256, 0, stream>>>(out, seg);
}